// Round 8
// baseline (751.873 us; speedup 1.0000x reference)
//
#include <hip/hip_runtime.h>
#include <stdint.h>

#define N_PTS 8192
#define N_B 8
#define NGROUP 512
#define GSIZE 32
#define BIGF 1e10f

#define K1_THREADS 256
#define K1_PPT 32
#define K1_WAVES 4

#define K2_THREADS 512
#define K2_PPT 16
#define K2_WAVES 8

// ---------------- DPP reductions ------------------------------------------------------
// gfx9 full-wave pattern: row_shr 1,2,4,8 + row_bcast15 (rmask 0xA) + row_bcast31 (0xC).
// bound_ctrl=false, old=src => invalid-source lanes keep own value (identity).

#define DPP_STEP_UMIN(ctrl, rmask)                                                 \
    { unsigned t = (unsigned)__builtin_amdgcn_update_dpp(                          \
            (int)v, (int)v, ctrl, rmask, 0xF, false);                              \
      v = (t < v) ? t : v; }

__device__ __forceinline__ unsigned wave_umin32(unsigned v) {
    DPP_STEP_UMIN(0x111, 0xF);
    DPP_STEP_UMIN(0x112, 0xF);
    DPP_STEP_UMIN(0x114, 0xF);
    DPP_STEP_UMIN(0x118, 0xF);
    DPP_STEP_UMIN(0x142, 0xA);
    DPP_STEP_UMIN(0x143, 0xC);
    return v;   // lane 63 valid
}

#define U64_DPP_STEP(ctrl, rmask, CMPOP)                                           \
    { unsigned lo_ = (unsigned)v, hi_ = (unsigned)(v >> 32);                       \
      unsigned olo = (unsigned)__builtin_amdgcn_update_dpp((int)lo_, (int)lo_, ctrl, rmask, 0xF, false); \
      unsigned ohi = (unsigned)__builtin_amdgcn_update_dpp((int)hi_, (int)hi_, ctrl, rmask, 0xF, false); \
      unsigned long long o = ((unsigned long long)ohi << 32) | olo;                \
      if (o CMPOP v) v = o; }

__device__ __forceinline__ unsigned long long wave_u64_max(unsigned long long v) {
    U64_DPP_STEP(0x111, 0xF, >);
    U64_DPP_STEP(0x112, 0xF, >);
    U64_DPP_STEP(0x114, 0xF, >);
    U64_DPP_STEP(0x118, 0xF, >);
    U64_DPP_STEP(0x142, 0xA, >);
    U64_DPP_STEP(0x143, 0xC, >);
    return v;   // lane 63 valid
}

__device__ __forceinline__ int rdlane63_i(int v) {
    return __builtin_amdgcn_readlane(v, 63);
}

// Exact (no-FMA) squared distance in numpy's evaluation order: (dx^2 + dy^2) + dz^2
__device__ __forceinline__ float sq_dist(float x, float y, float z,
                                         float cx, float cy, float cz) {
    float dx = __fsub_rn(x, cx);
    float dy = __fsub_rn(y, cy);
    float dz = __fsub_rn(z, cz);
    return __fadd_rn(__fadd_rn(__fmul_rn(dx, dx), __fmul_rn(dy, dy)), __fmul_rn(dz, dz));
}

__device__ __forceinline__ unsigned fxform(unsigned u) {
    return u ^ (unsigned)(((int)u >> 31) | 0x80000000);
}

// bitonic sort (ascending) of an N-element register array of u64
template<int N>
__device__ __forceinline__ void bitonic_sort(unsigned long long* a) {
#pragma unroll
    for (int k = 2; k <= N; k <<= 1) {
#pragma unroll
        for (int j = k >> 1; j > 0; j >>= 1) {
#pragma unroll
            for (int i = 0; i < N; ++i) {
                int ixj = i ^ j;
                if (ixj > i) {
                    bool up = ((i & k) == 0);
                    unsigned long long x = a[i], y = a[ixj];
                    bool sw = up ? (x > y) : (x < y);
                    if (sw) { a[i] = y; a[ixj] = x; }
                }
            }
        }
    }
}

// ---------------- Kernel 1: farthest point sampling, one block per batch ---------------
// 256 threads = 4 waves = 1 wave/SIMD. (256,1): full VGPR budget -> no scratch spills.
extern "C" __global__ __launch_bounds__(K1_THREADS, 1) void fps_kernel(
    const float* __restrict__ xyz, int* __restrict__ fps_idx)
{
    const int b   = blockIdx.x;
    const int tid = threadIdx.x;
    const float* base = xyz + (size_t)b * N_PTS * 6;
    const float4* b4 = (const float4*)base;

    __shared__ float lx[N_PTS], ly[N_PTS], lz[N_PTS];
    __shared__ unsigned part[2][K1_WAVES][8];   // {keyLo, keyHi, x, y, z} 32B stride

    // 32 consecutive points per thread via 48 float4 loads (all bytes used)
    float sx[K1_PPT], sy[K1_PPT], sz[K1_PPT], dd[K1_PPT];
    const int tb = tid * 48;
#pragma unroll
    for (int c = 0; c < 8; ++c) {
        float4 f0 = b4[tb + c * 6 + 0];
        float4 f1 = b4[tb + c * 6 + 1];
        float4 f2 = b4[tb + c * 6 + 2];
        float4 f3 = b4[tb + c * 6 + 3];
        float4 f4 = b4[tb + c * 6 + 4];
        float4 f5 = b4[tb + c * 6 + 5];
        sx[c*4+0] = f0.x; sy[c*4+0] = f0.y; sz[c*4+0] = f0.z;
        sx[c*4+1] = f1.z; sy[c*4+1] = f1.w; sz[c*4+1] = f2.x;
        sx[c*4+2] = f3.x; sy[c*4+2] = f3.y; sz[c*4+2] = f3.z;
        sx[c*4+3] = f4.z; sy[c*4+3] = f4.w; sz[c*4+3] = f5.x;
    }
    // swizzled staging: point p = tid*32+i lives at A(p) = (i<<8) + tid -> conflict-free
#pragma unroll
    for (int i = 0; i < K1_PPT; ++i) {
        int a = (i << 8) + tid;
        lx[a] = sx[i]; ly[a] = sy[i]; lz[a] = sz[i];
        dd[i] = BIGF;
    }
    __syncthreads();

    const int lane = tid & 63;
    const int wid  = tid >> 6;
    unsigned cur = 0;
    float cx = lx[0], cy = ly[0], cz = lz[0];

    const unsigned lobase = 0xFFFFFFFFu - (unsigned)(tid * K1_PPT);

    for (int it = 0; it < NGROUP; ++it) {
        if (tid == 0) fps_idx[b * NGROUP + it] = (int)cur;
        if (it == NGROUP - 1) break;

        // min-update (independent chains, full ILP)
#pragma unroll
        for (int i = 0; i < K1_PPT; ++i) {
            float d = sq_dist(sx[i], sy[i], sz[i], cx, cy, cz);
            dd[i] = fminf(dd[i], d);
        }

        // in-thread u64 key tree-max: key = distBits<<32 | (~globalIdx)
        // (max key == max dist, ties -> smaller index; tree is value-exact)
        unsigned long long k[K1_PPT];
#pragma unroll
        for (int i = 0; i < K1_PPT; ++i)
            k[i] = ((unsigned long long)__float_as_uint(dd[i]) << 32)
                 | (unsigned long long)(lobase - (unsigned)i);
#pragma unroll
        for (int s = K1_PPT / 2; s >= 1; s >>= 1)
#pragma unroll
            for (int i = 0; i < K1_PPT; ++i)   // only i<s used; guard below
                if (i < s && k[i + s] > k[i]) k[i] = k[i + s];

        // wave max (single 6-step u64 DPP chain), lane 63 valid
        unsigned long long bk = wave_u64_max(k[0]);

        if (lane == 63) {
            unsigned widx = 0xFFFFFFFFu - (unsigned)bk;
            int wa = (int)(((widx & 31u) << 8) + (widx >> 5));
            unsigned* pp = part[it & 1][wid];
            pp[0] = (unsigned)bk;
            pp[1] = (unsigned)(bk >> 32);
            pp[2] = __float_as_uint(lx[wa]);
            pp[3] = __float_as_uint(ly[wa]);
            pp[4] = __float_as_uint(lz[wa]);
        }
        __syncthreads();

        // block reduce over 4 partials: lanes 0..3 hold parts 0..3; max valid in lane 3
        const unsigned* pp = part[it & 1][lane & 3];
        unsigned kl = pp[0], kh = pp[1];
        float xx = __uint_as_float(pp[2]);
        float yy = __uint_as_float(pp[3]);
        float zz = __uint_as_float(pp[4]);
        unsigned long long v = ((unsigned long long)kh << 32) | kl;
        U64_DPP_STEP(0x111, 0xF, >);
        U64_DPP_STEP(0x112, 0xF, >);
        unsigned wkl = (unsigned)__builtin_amdgcn_readlane((int)(unsigned)v, 3);
        cur = 0xFFFFFFFFu - wkl;
        int W = (int)(cur >> 11);   // 2048 pts per wave -> winning wave id
        cx = __int_as_float(__builtin_amdgcn_readlane(__float_as_int(xx), W));
        cy = __int_as_float(__builtin_amdgcn_readlane(__float_as_int(yy), W));
        cz = __int_as_float(__builtin_amdgcn_readlane(__float_as_int(zz), W));
    }
}

// ---------------- Kernel 2: 32-NN per (batch, group) ----------------------------------
extern "C" __global__ __launch_bounds__(K2_THREADS, 2) void knn_kernel(
    const float* __restrict__ xyz, const int* __restrict__ fps_idx,
    float* __restrict__ out)
{
    const int bg  = blockIdx.x;
    const int b   = bg >> 9;
    const int g   = bg & (NGROUP - 1);
    const int tid = threadIdx.x;
    const float* base = xyz + (size_t)b * N_PTS * 6;

    const int q  = fps_idx[b * NGROUP + g];
    const int qq = __builtin_amdgcn_readfirstlane(q);
    const float cx = base[qq * 6 + 0];
    const float cy = base[qq * 6 + 1];
    const float cz = base[qq * 6 + 2];
    // ||c||^2: separate square, left-assoc add, NO FMA
    const float cn = __fadd_rn(__fadd_rn(__fmul_rn(cx, cx), __fmul_rn(cy, cy)),
                               __fmul_rn(cz, cz));

    const float4* b4 = (const float4*)base;
    const int tb = tid * 24;

    unsigned long long keys[K2_PPT];

#pragma unroll
    for (int c = 0; c < 4; ++c) {
        float4 f0 = b4[tb + c * 6 + 0];
        float4 f1 = b4[tb + c * 6 + 1];
        float4 f2 = b4[tb + c * 6 + 2];
        float4 f3 = b4[tb + c * 6 + 3];
        float4 f4 = b4[tb + c * 6 + 4];
        float4 f5 = b4[tb + c * 6 + 5];
        float X[4] = {f0.x, f1.z, f3.x, f4.z};
        float Y[4] = {f0.y, f1.w, f3.y, f4.w};
        float Z[4] = {f0.z, f2.x, f3.z, f5.x};
#pragma unroll
        for (int j = 0; j < 4; ++j) {
            float x = X[j], y = Y[j], z = Z[j];
            // ||x||^2: NO FMA (separate numpy op)
            float xn  = __fadd_rn(__fadd_rn(__fmul_rn(x, x), __fmul_rn(y, y)), __fmul_rn(z, z));
            // einsum dot: FMA chain ascending in k (XLA dot path)
            float dot = __fmul_rn(cx, x);
            dot = __fmaf_rn(cy, y, dot);
            dot = __fmaf_rn(cz, z, dot);
            // d2 = (cn - 2*dot) + xn   (left to right, no FMA)
            float d2  = __fadd_rn(__fsub_rn(cn, __fmul_rn(2.0f, dot)), xn);
            int p = tid * K2_PPT + c * 4 + j;
            keys[c * 4 + j] =
                ((unsigned long long)fxform(__float_as_uint(d2)) << 32) | (unsigned)p;
        }
    }

    // per-thread ascending sort; spill sorted list to LDS for rare deep heads
    bitonic_sort<K2_PPT>(keys);

    __shared__ unsigned long long skeys[K2_PPT][K2_THREADS];   // 64 KB
    __shared__ unsigned long long wtop[K2_WAVES][GSIZE];       // 2 KB
#pragma unroll
    for (int i = 0; i < K2_PPT; ++i) skeys[i][tid] = keys[i];

    const int wid  = tid >> 6;
    const int lane = tid & 63;

    // per-wave top-32 extraction: u32 DPP min on d2 bits; idx via ballot fast path
    {
        unsigned long long cand = keys[0];
        unsigned w = 0;
        for (int r = 0; r < GSIZE; ++r) {
            unsigned ch = (unsigned)(cand >> 32);
            unsigned whd = (unsigned)rdlane63_i((int)wave_umin32(ch));
            unsigned long long bal = __ballot(ch == whd);
            unsigned wl;
            if (__popcll(bal) == 1) {
                int L = (int)(__ffsll((long long)bal) - 1);
                wl = (unsigned)__builtin_amdgcn_readlane((int)(unsigned)cand, L);
            } else {
                unsigned cl = (ch == whd) ? (unsigned)cand : 0xFFFFFFFFu;
                wl = (unsigned)rdlane63_i((int)wave_umin32(cl));
            }
            unsigned long long wkey = ((unsigned long long)whd << 32) | wl;
            if (lane == 0) wtop[wid][r] = wkey;
            if (cand == wkey) {   // exactly one lane (keys unique)
                ++w;
                unsigned long long nc;
                if (w == 1)      nc = keys[1];
                else if (w == 2) nc = keys[2];
                else if (w == 3) nc = keys[3];
                else if (w < K2_PPT) nc = skeys[w][tid];   // rare
                else nc = ~0ull;
                cand = nc;
            }
        }
    }
    __syncthreads();
    if (wid != 0) return;

    // wave 0 merges 8 sorted top-32 lists: lane takes 4 consecutive (pre-sorted) elems
    unsigned long long mk0 = wtop[lane >> 3][(lane & 7) * 4 + 0];
    unsigned long long mk1 = wtop[lane >> 3][(lane & 7) * 4 + 1];
    unsigned long long mk2 = wtop[lane >> 3][(lane & 7) * 4 + 2];
    unsigned long long mk3 = wtop[lane >> 3][(lane & 7) * 4 + 3];

    unsigned myp = 0;
    {
        unsigned long long cand = mk0;
        unsigned w = 0;
        for (int r = 0; r < GSIZE; ++r) {
            unsigned ch = (unsigned)(cand >> 32);
            unsigned whd = (unsigned)rdlane63_i((int)wave_umin32(ch));
            unsigned long long bal = __ballot(ch == whd);
            unsigned wl;
            if (__popcll(bal) == 1) {
                int L = (int)(__ffsll((long long)bal) - 1);
                wl = (unsigned)__builtin_amdgcn_readlane((int)(unsigned)cand, L);
            } else {
                unsigned cl = (ch == whd) ? (unsigned)cand : 0xFFFFFFFFu;
                wl = (unsigned)rdlane63_i((int)wave_umin32(cl));
            }
            unsigned long long wkey = ((unsigned long long)whd << 32) | wl;
            if (lane == r) myp = wl;
            if (cand == wkey) {
                ++w;
                cand = (w == 1) ? mk1 : (w == 2) ? mk2 : (w == 3) ? mk3 : ~0ull;
            }
        }
    }

    // ---- outputs (wave 0 only) ----
    const int OFF1 = N_B * NGROUP * GSIZE * 3;   // neigh_attr
    const int OFF2 = 2 * OFF1;                   // center
    const int OFF3 = OFF2 + N_B * NGROUP * 3;    // center_attribute

    if (lane < GSIZE) {
        unsigned p = myp;
        float x  = base[p * 6 + 0];
        float y  = base[p * 6 + 1];
        float z  = base[p * 6 + 2];
        float a0 = base[p * 6 + 3];
        float a1 = base[p * 6 + 4];
        float a2 = base[p * 6 + 5];
        size_t o = ((size_t)(b * NGROUP + g) * GSIZE + lane) * 3;
        out[o + 0] = __fsub_rn(x, cx);
        out[o + 1] = __fsub_rn(y, cy);
        out[o + 2] = __fsub_rn(z, cz);
        out[OFF1 + o + 0] = a0;
        out[OFF1 + o + 1] = a1;
        out[OFF1 + o + 2] = a2;
    } else if (lane == GSIZE) {
        size_t o = (size_t)(b * NGROUP + g) * 3;
        out[OFF2 + o + 0] = cx;
        out[OFF2 + o + 1] = cy;
        out[OFF2 + o + 2] = cz;
        out[OFF3 + o + 0] = base[qq * 6 + 3];
        out[OFF3 + o + 1] = base[qq * 6 + 4];
        out[OFF3 + o + 2] = base[qq * 6 + 5];
    }
}

extern "C" void kernel_launch(void* const* d_in, const int* in_sizes, int n_in,
                              void* d_out, int out_size, void* d_ws, size_t ws_size,
                              hipStream_t stream) {
    const float* xyz = (const float*)d_in[0];
    float* out = (float*)d_out;
    int* fps_idx = (int*)d_ws;   // 8*512 ints = 16 KB

    fps_kernel<<<N_B, K1_THREADS, 0, stream>>>(xyz, fps_idx);
    knn_kernel<<<N_B * NGROUP, K2_THREADS, 0, stream>>>(xyz, fps_idx, out);
}

// Round 9
// 679.096 us; speedup vs baseline: 1.1072x; 1.1072x over previous
//
#include <hip/hip_runtime.h>
#include <stdint.h>

#define N_PTS 8192
#define N_B 8
#define NGROUP 512
#define GSIZE 32
#define BIGF 1e10f

#define K1_THREADS 512
#define K1_PPT 16
#define K1_WAVES 8

#define K2_THREADS 512
#define K2_PPT 16
#define K2_WAVES 8

// ---------------- DPP reductions ------------------------------------------------------
// gfx9 full-wave pattern: row_shr 1,2,4,8 + row_bcast15 (rmask 0xA) + row_bcast31 (0xC).
// bound_ctrl=false, old=src => invalid-source lanes keep own value (identity).

#define DPP_STEP_UMIN(ctrl, rmask)                                                 \
    { unsigned t = (unsigned)__builtin_amdgcn_update_dpp(                          \
            (int)v, (int)v, ctrl, rmask, 0xF, false);                              \
      v = (t < v) ? t : v; }

__device__ __forceinline__ unsigned wave_umin32(unsigned v) {
    DPP_STEP_UMIN(0x111, 0xF);
    DPP_STEP_UMIN(0x112, 0xF);
    DPP_STEP_UMIN(0x114, 0xF);
    DPP_STEP_UMIN(0x118, 0xF);
    DPP_STEP_UMIN(0x142, 0xA);
    DPP_STEP_UMIN(0x143, 0xC);
    return v;   // lane 63 valid
}

#define DPP_STEP_FMAX(ctrl, rmask)                                                 \
    v = fmaxf(v, __int_as_float(__builtin_amdgcn_update_dpp(                       \
            __float_as_int(v), __float_as_int(v), ctrl, rmask, 0xF, false)))

__device__ __forceinline__ float wave_fmax(float v) {
    DPP_STEP_FMAX(0x111, 0xF);
    DPP_STEP_FMAX(0x112, 0xF);
    DPP_STEP_FMAX(0x114, 0xF);
    DPP_STEP_FMAX(0x118, 0xF);
    DPP_STEP_FMAX(0x142, 0xA);
    DPP_STEP_FMAX(0x143, 0xC);
    return v;   // lane 63 valid
}

#define U64_DPP_STEP(ctrl, rmask, CMPOP)                                           \
    { unsigned lo_ = (unsigned)v, hi_ = (unsigned)(v >> 32);                       \
      unsigned olo = (unsigned)__builtin_amdgcn_update_dpp((int)lo_, (int)lo_, ctrl, rmask, 0xF, false); \
      unsigned ohi = (unsigned)__builtin_amdgcn_update_dpp((int)hi_, (int)hi_, ctrl, rmask, 0xF, false); \
      unsigned long long o = ((unsigned long long)ohi << 32) | olo;                \
      if (o CMPOP v) v = o; }

__device__ __forceinline__ int rdlane63_i(int v) {
    return __builtin_amdgcn_readlane(v, 63);
}

// Exact (no-FMA) squared distance in numpy's evaluation order: (dx^2 + dy^2) + dz^2
__device__ __forceinline__ float sq_dist(float x, float y, float z,
                                         float cx, float cy, float cz) {
    float dx = __fsub_rn(x, cx);
    float dy = __fsub_rn(y, cy);
    float dz = __fsub_rn(z, cz);
    return __fadd_rn(__fadd_rn(__fmul_rn(dx, dx), __fmul_rn(dy, dy)), __fmul_rn(dz, dz));
}

__device__ __forceinline__ unsigned fxform(unsigned u) {
    return u ^ (unsigned)(((int)u >> 31) | 0x80000000);
}

// bitonic sort (ascending) of an N-element register array of u64
template<int N>
__device__ __forceinline__ void bitonic_sort(unsigned long long* a) {
#pragma unroll
    for (int k = 2; k <= N; k <<= 1) {
#pragma unroll
        for (int j = k >> 1; j > 0; j >>= 1) {
#pragma unroll
            for (int i = 0; i < N; ++i) {
                int ixj = i ^ j;
                if (ixj > i) {
                    bool up = ((i & k) == 0);
                    unsigned long long x = a[i], y = a[ixj];
                    bool sw = up ? (x > y) : (x < y);
                    if (sw) { a[i] = y; a[ixj] = x; }
                }
            }
        }
    }
}

// ---------------- Kernel 1: farthest point sampling, one block per batch ---------------
// 512 threads, 16 pts/thread: arrays = 64 VGPRs -> no spill pressure (R4 evidence).
extern "C" __global__ __launch_bounds__(K1_THREADS, 1) void fps_kernel(
    const float* __restrict__ xyz, int* __restrict__ fps_idx)
{
    const int b   = blockIdx.x;
    const int tid = threadIdx.x;
    const float* base = xyz + (size_t)b * N_PTS * 6;
    const float4* b4 = (const float4*)base;

    __shared__ float lx[N_PTS], ly[N_PTS], lz[N_PTS];
    __shared__ unsigned part[2][K1_WAVES][8];   // {keyLo, keyHi, x, y, z} 32B stride

    // 16 consecutive points per thread via 24 float4 loads (all bytes used)
    float sx[K1_PPT], sy[K1_PPT], sz[K1_PPT], dd[K1_PPT];
    const int tb = tid * 24;
#pragma unroll
    for (int c = 0; c < 4; ++c) {
        float4 f0 = b4[tb + c * 6 + 0];
        float4 f1 = b4[tb + c * 6 + 1];
        float4 f2 = b4[tb + c * 6 + 2];
        float4 f3 = b4[tb + c * 6 + 3];
        float4 f4 = b4[tb + c * 6 + 4];
        float4 f5 = b4[tb + c * 6 + 5];
        sx[c*4+0] = f0.x; sy[c*4+0] = f0.y; sz[c*4+0] = f0.z;
        sx[c*4+1] = f1.z; sy[c*4+1] = f1.w; sz[c*4+1] = f2.x;
        sx[c*4+2] = f3.x; sy[c*4+2] = f3.y; sz[c*4+2] = f3.z;
        sx[c*4+3] = f4.z; sy[c*4+3] = f4.w; sz[c*4+3] = f5.x;
    }
    // swizzled staging: point p = tid*16+i lives at A(p) = (i<<9) + tid -> conflict-free
#pragma unroll
    for (int i = 0; i < K1_PPT; ++i) {
        int a = (i << 9) + tid;
        lx[a] = sx[i]; ly[a] = sy[i]; lz[a] = sz[i];
        dd[i] = BIGF;
    }
    __syncthreads();

    const int lane = tid & 63;
    const int wid  = tid >> 6;
    unsigned cur = 0;
    float cx = lx[0], cy = ly[0], cz = lz[0];   // point 0: A(0)=0

    for (int it = 0; it < NGROUP; ++it) {
        if (tid == 0) fps_idx[b * NGROUP + it] = (int)cur;
        if (it == NGROUP - 1) break;

        // min-update (independent chains, full ILP)
#pragma unroll
        for (int i = 0; i < K1_PPT; ++i) {
            float d = sq_dist(sx[i], sy[i], sz[i], cx, cy, cz);
            dd[i] = fminf(dd[i], d);
        }

        // thread-local max via tree (value-exact; index recovered by post-scan)
        float t8[8];
#pragma unroll
        for (int j = 0; j < 8; ++j) t8[j] = fmaxf(dd[2*j], dd[2*j+1]);
        float t4a = fmaxf(t8[0], t8[1]), t4b = fmaxf(t8[2], t8[3]);
        float t4c = fmaxf(t8[4], t8[5]), t4d = fmaxf(t8[6], t8[7]);
        float bestd = fmaxf(fmaxf(t4a, t4b), fmaxf(t4c, t4d));

        // wave max, then first matching lane / smallest local slot (exact argmax tie-break)
        float wm = __int_as_float(rdlane63_i(__float_as_int(wave_fmax(bestd))));
        int ii = K1_PPT;
#pragma unroll
        for (int i = K1_PPT - 1; i >= 0; --i) if (dd[i] == wm) ii = i;
        unsigned long long bal = __ballot(ii < K1_PPT);
        int L = (int)(__ffsll((long long)bal) - 1);
        unsigned widx = (unsigned)__builtin_amdgcn_readlane((int)(unsigned)(tid * K1_PPT + ii), L);

        if (lane == 63) {
            int wa = (int)(((widx & 15u) << 9) + (widx >> 4));
            unsigned* pp = part[it & 1][wid];
            pp[0] = 0xFFFFFFFFu - widx;
            pp[1] = __float_as_uint(wm);
            pp[2] = __float_as_uint(lx[wa]);
            pp[3] = __float_as_uint(ly[wa]);
            pp[4] = __float_as_uint(lz[wa]);
        }
        __syncthreads();

        // block reduce over 8 partials: lanes 0..7 hold parts 0..7; max valid in lane 7
        const unsigned* pp = part[it & 1][lane & 7];
        unsigned kl = pp[0], kh = pp[1];
        float xx = __uint_as_float(pp[2]);
        float yy = __uint_as_float(pp[3]);
        float zz = __uint_as_float(pp[4]);
        unsigned long long v = ((unsigned long long)kh << 32) | kl;
        U64_DPP_STEP(0x111, 0xF, >);
        U64_DPP_STEP(0x112, 0xF, >);
        U64_DPP_STEP(0x114, 0xF, >);
        unsigned wkl = (unsigned)__builtin_amdgcn_readlane((int)(unsigned)v, 7);
        cur = 0xFFFFFFFFu - wkl;
        int W = (int)(cur >> 10);   // 1024 pts per wave -> winning wave id
        cx = __int_as_float(__builtin_amdgcn_readlane(__float_as_int(xx), W));
        cy = __int_as_float(__builtin_amdgcn_readlane(__float_as_int(yy), W));
        cz = __int_as_float(__builtin_amdgcn_readlane(__float_as_int(zz), W));
    }
}

// ---------------- Kernel 2: 32-NN per (batch, group) ----------------------------------
// Per-wave DPP top-32 extraction (sorted), then PARALLEL rank-merge of the 8 sorted
// lists (binary-search ranks; keys unique => exact), then gather/write.
extern "C" __global__ __launch_bounds__(K2_THREADS, 2) void knn_kernel(
    const float* __restrict__ xyz, const int* __restrict__ fps_idx,
    float* __restrict__ out)
{
    const int bg  = blockIdx.x;
    const int b   = bg >> 9;
    const int g   = bg & (NGROUP - 1);
    const int tid = threadIdx.x;
    const float* base = xyz + (size_t)b * N_PTS * 6;

    const int q  = fps_idx[b * NGROUP + g];
    const int qq = __builtin_amdgcn_readfirstlane(q);
    const float cx = base[qq * 6 + 0];
    const float cy = base[qq * 6 + 1];
    const float cz = base[qq * 6 + 2];
    // ||c||^2: separate square, left-assoc add, NO FMA
    const float cn = __fadd_rn(__fadd_rn(__fmul_rn(cx, cx), __fmul_rn(cy, cy)),
                               __fmul_rn(cz, cz));

    const float4* b4 = (const float4*)base;
    const int tb = tid * 24;

    unsigned long long keys[K2_PPT];

#pragma unroll
    for (int c = 0; c < 4; ++c) {
        float4 f0 = b4[tb + c * 6 + 0];
        float4 f1 = b4[tb + c * 6 + 1];
        float4 f2 = b4[tb + c * 6 + 2];
        float4 f3 = b4[tb + c * 6 + 3];
        float4 f4 = b4[tb + c * 6 + 4];
        float4 f5 = b4[tb + c * 6 + 5];
        float X[4] = {f0.x, f1.z, f3.x, f4.z};
        float Y[4] = {f0.y, f1.w, f3.y, f4.w};
        float Z[4] = {f0.z, f2.x, f3.z, f5.x};
#pragma unroll
        for (int j = 0; j < 4; ++j) {
            float x = X[j], y = Y[j], z = Z[j];
            float xn  = __fadd_rn(__fadd_rn(__fmul_rn(x, x), __fmul_rn(y, y)), __fmul_rn(z, z));
            float dot = __fmul_rn(cx, x);
            dot = __fmaf_rn(cy, y, dot);
            dot = __fmaf_rn(cz, z, dot);
            float d2  = __fadd_rn(__fsub_rn(cn, __fmul_rn(2.0f, dot)), xn);
            int p = tid * K2_PPT + c * 4 + j;
            keys[c * 4 + j] =
                ((unsigned long long)fxform(__float_as_uint(d2)) << 32) | (unsigned)p;
        }
    }

    bitonic_sort<K2_PPT>(keys);

    __shared__ unsigned long long skeys[12][K2_THREADS];   // heads 4..15, 48 KB
    __shared__ unsigned long long wtop[K2_WAVES][GSIZE];   // 2 KB
    __shared__ unsigned nlist[GSIZE];
#pragma unroll
    for (int i = 4; i < K2_PPT; ++i) skeys[i - 4][tid] = keys[i];

    const int wid  = tid >> 6;
    const int lane = tid & 63;

    // per-wave top-32 extraction (ascending into wtop[wid])
    {
        unsigned long long cand = keys[0];
        unsigned w = 0;
        for (int r = 0; r < GSIZE; ++r) {
            unsigned ch = (unsigned)(cand >> 32);
            unsigned whd = (unsigned)rdlane63_i((int)wave_umin32(ch));
            unsigned long long bal = __ballot(ch == whd);
            unsigned wl;
            if (__popcll(bal) == 1) {
                int L = (int)(__ffsll((long long)bal) - 1);
                wl = (unsigned)__builtin_amdgcn_readlane((int)(unsigned)cand, L);
            } else {
                unsigned cl = (ch == whd) ? (unsigned)cand : 0xFFFFFFFFu;
                wl = (unsigned)rdlane63_i((int)wave_umin32(cl));
            }
            unsigned long long wkey = ((unsigned long long)whd << 32) | wl;
            if (lane == 0) wtop[wid][r] = wkey;
            if (cand == wkey) {   // exactly one lane (keys unique)
                ++w;
                unsigned long long nc;
                if (w == 1)      nc = keys[1];
                else if (w == 2) nc = keys[2];
                else if (w == 3) nc = keys[3];
                else if (w < K2_PPT) nc = skeys[w - 4][tid];
                else nc = ~0ull;
                cand = nc;
            }
        }
    }
    __syncthreads();

    // parallel rank-merge: 256 threads, one candidate each; rank = sum of lower_bounds
    if (tid < K2_WAVES * GSIZE) {
        const int w8 = tid >> 5, i = tid & 31;
        unsigned long long e = wtop[w8][i];
        int rank = 0;
#pragma unroll
        for (int l = 0; l < K2_WAVES; ++l) {
            const unsigned long long* arr = wtop[l];
            int lo = 0;
            if (arr[15]     < e) lo = 16;
            if (arr[lo + 7] < e) lo += 8;
            if (arr[lo + 3] < e) lo += 4;
            if (arr[lo + 1] < e) lo += 2;
            if (arr[lo]     < e) lo += 1;
            rank += lo;
        }
        if (rank < GSIZE) nlist[rank] = (unsigned)e;
    }
    __syncthreads();

    // ---- outputs ----
    const int OFF1 = N_B * NGROUP * GSIZE * 3;   // neigh_attr
    const int OFF2 = 2 * OFF1;                   // center
    const int OFF3 = OFF2 + N_B * NGROUP * 3;    // center_attribute

    if (tid < GSIZE) {
        unsigned p = nlist[tid];
        float x  = base[p * 6 + 0];
        float y  = base[p * 6 + 1];
        float z  = base[p * 6 + 2];
        float a0 = base[p * 6 + 3];
        float a1 = base[p * 6 + 4];
        float a2 = base[p * 6 + 5];
        size_t o = ((size_t)(b * NGROUP + g) * GSIZE + tid) * 3;
        out[o + 0] = __fsub_rn(x, cx);
        out[o + 1] = __fsub_rn(y, cy);
        out[o + 2] = __fsub_rn(z, cz);
        out[OFF1 + o + 0] = a0;
        out[OFF1 + o + 1] = a1;
        out[OFF1 + o + 2] = a2;
    } else if (tid == GSIZE) {
        size_t o = (size_t)(b * NGROUP + g) * 3;
        out[OFF2 + o + 0] = cx;
        out[OFF2 + o + 1] = cy;
        out[OFF2 + o + 2] = cz;
        out[OFF3 + o + 0] = base[qq * 6 + 3];
        out[OFF3 + o + 1] = base[qq * 6 + 4];
        out[OFF3 + o + 2] = base[qq * 6 + 5];
    }
}

extern "C" void kernel_launch(void* const* d_in, const int* in_sizes, int n_in,
                              void* d_out, int out_size, void* d_ws, size_t ws_size,
                              hipStream_t stream) {
    const float* xyz = (const float*)d_in[0];
    float* out = (float*)d_out;
    int* fps_idx = (int*)d_ws;   // 8*512 ints = 16 KB

    fps_kernel<<<N_B, K1_THREADS, 0, stream>>>(xyz, fps_idx);
    knn_kernel<<<N_B * NGROUP, K2_THREADS, 0, stream>>>(xyz, fps_idx, out);
}

// Round 10
// 623.363 us; speedup vs baseline: 1.2062x; 1.0894x over previous
//
#include <hip/hip_runtime.h>
#include <stdint.h>

#define N_PTS 8192
#define N_B 8
#define NGROUP 512
#define GSIZE 32
#define BIGF 1e10f

#define K1_THREADS 256
#define K1_PPT 32
#define K1_WAVES 4

#define K2_THREADS 512
#define K2_PPT 16
#define K2_WAVES 8

// ---------------- DPP reductions ------------------------------------------------------
// gfx9 full-wave pattern: row_shr 1,2,4,8 + row_bcast15 (rmask 0xA) + row_bcast31 (0xC).
// bound_ctrl=false, old=src => invalid-source lanes keep own value (identity).

#define DPP_STEP_UMIN(ctrl, rmask)                                                 \
    { unsigned t = (unsigned)__builtin_amdgcn_update_dpp(                          \
            (int)v, (int)v, ctrl, rmask, 0xF, false);                              \
      v = (t < v) ? t : v; }

__device__ __forceinline__ unsigned wave_umin32(unsigned v) {
    DPP_STEP_UMIN(0x111, 0xF);
    DPP_STEP_UMIN(0x112, 0xF);
    DPP_STEP_UMIN(0x114, 0xF);
    DPP_STEP_UMIN(0x118, 0xF);
    DPP_STEP_UMIN(0x142, 0xA);
    DPP_STEP_UMIN(0x143, 0xC);
    return v;   // lane 63 valid
}

#define DPP_STEP_FMAX(ctrl, rmask)                                                 \
    v = fmaxf(v, __int_as_float(__builtin_amdgcn_update_dpp(                       \
            __float_as_int(v), __float_as_int(v), ctrl, rmask, 0xF, false)))

__device__ __forceinline__ float wave_fmax(float v) {
    DPP_STEP_FMAX(0x111, 0xF);
    DPP_STEP_FMAX(0x112, 0xF);
    DPP_STEP_FMAX(0x114, 0xF);
    DPP_STEP_FMAX(0x118, 0xF);
    DPP_STEP_FMAX(0x142, 0xA);
    DPP_STEP_FMAX(0x143, 0xC);
    return v;   // lane 63 valid
}

#define U64_DPP_STEP(ctrl, rmask, CMPOP)                                           \
    { unsigned lo_ = (unsigned)v, hi_ = (unsigned)(v >> 32);                       \
      unsigned olo = (unsigned)__builtin_amdgcn_update_dpp((int)lo_, (int)lo_, ctrl, rmask, 0xF, false); \
      unsigned ohi = (unsigned)__builtin_amdgcn_update_dpp((int)hi_, (int)hi_, ctrl, rmask, 0xF, false); \
      unsigned long long o = ((unsigned long long)ohi << 32) | olo;                \
      if (o CMPOP v) v = o; }

__device__ __forceinline__ int rdlane63_i(int v) {
    return __builtin_amdgcn_readlane(v, 63);
}

// Exact (no-FMA) squared distance in numpy's evaluation order: (dx^2 + dy^2) + dz^2
__device__ __forceinline__ float sq_dist(float x, float y, float z,
                                         float cx, float cy, float cz) {
    float dx = __fsub_rn(x, cx);
    float dy = __fsub_rn(y, cy);
    float dz = __fsub_rn(z, cz);
    return __fadd_rn(__fadd_rn(__fmul_rn(dx, dx), __fmul_rn(dy, dy)), __fmul_rn(dz, dz));
}

__device__ __forceinline__ unsigned fxform(unsigned u) {
    return u ^ (unsigned)(((int)u >> 31) | 0x80000000);
}

// bitonic sort (ascending) of an N-element register array of u64
template<int N>
__device__ __forceinline__ void bitonic_sort(unsigned long long* a) {
#pragma unroll
    for (int k = 2; k <= N; k <<= 1) {
#pragma unroll
        for (int j = k >> 1; j > 0; j >>= 1) {
#pragma unroll
            for (int i = 0; i < N; ++i) {
                int ixj = i ^ j;
                if (ixj > i) {
                    bool up = ((i & k) == 0);
                    unsigned long long x = a[i], y = a[ixj];
                    bool sw = up ? (x > y) : (x < y);
                    if (sw) { a[i] = y; a[ixj] = x; }
                }
            }
        }
    }
}

// ---------------- Kernel 1: farthest point sampling, one block per batch ---------------
// R7 structure (best measured: 485 us) + (256,1) launch bounds to eliminate spills.
extern "C" __global__ __launch_bounds__(K1_THREADS, 1) void fps_kernel(
    const float* __restrict__ xyz, int* __restrict__ fps_idx)
{
    const int b   = blockIdx.x;
    const int tid = threadIdx.x;
    const float* base = xyz + (size_t)b * N_PTS * 6;
    const float4* b4 = (const float4*)base;

    __shared__ float lx[N_PTS], ly[N_PTS], lz[N_PTS];
    __shared__ unsigned part[2][K1_WAVES][8];   // {~idx, distBits, x, y, z} 32B stride

    // 32 consecutive points per thread via 48 float4 loads (all bytes used)
    float sx[K1_PPT], sy[K1_PPT], sz[K1_PPT], dd[K1_PPT];
    const int tb = tid * 48;
#pragma unroll
    for (int c = 0; c < 8; ++c) {
        float4 f0 = b4[tb + c * 6 + 0];
        float4 f1 = b4[tb + c * 6 + 1];
        float4 f2 = b4[tb + c * 6 + 2];
        float4 f3 = b4[tb + c * 6 + 3];
        float4 f4 = b4[tb + c * 6 + 4];
        float4 f5 = b4[tb + c * 6 + 5];
        sx[c*4+0] = f0.x; sy[c*4+0] = f0.y; sz[c*4+0] = f0.z;
        sx[c*4+1] = f1.z; sy[c*4+1] = f1.w; sz[c*4+1] = f2.x;
        sx[c*4+2] = f3.x; sy[c*4+2] = f3.y; sz[c*4+2] = f3.z;
        sx[c*4+3] = f4.z; sy[c*4+3] = f4.w; sz[c*4+3] = f5.x;
    }
    // swizzled staging: point p = tid*32+i lives at A(p) = (i<<8) + tid -> conflict-free
#pragma unroll
    for (int i = 0; i < K1_PPT; ++i) {
        int a = (i << 8) + tid;
        lx[a] = sx[i]; ly[a] = sy[i]; lz[a] = sz[i];
        dd[i] = BIGF;
    }
    __syncthreads();

    const int lane = tid & 63;
    const int wid  = tid >> 6;
    unsigned cur = 0;
    float cx = lx[0], cy = ly[0], cz = lz[0];   // point 0: A(0)=0

    for (int it = 0; it < NGROUP; ++it) {
        if (tid == 0) fps_idx[b * NGROUP + it] = (int)cur;
        if (it == NGROUP - 1) break;

        // min-update + inline first-max tracking (ascending i == ascending global idx)
        float bestd = -1.0f;
        unsigned besti = 0;
#pragma unroll
        for (int i = 0; i < K1_PPT; ++i) {
            float d = sq_dist(sx[i], sy[i], sz[i], cx, cy, cz);
            dd[i] = fminf(dd[i], d);
            bool gt = dd[i] > bestd;
            bestd = gt ? dd[i] : bestd;
            besti = gt ? (unsigned)i : besti;
        }
        unsigned bestp = (unsigned)tid * K1_PPT + besti;

        // wave argmax: f32 DPP max, then first tied lane (= smallest global index)
        float wm = __int_as_float(rdlane63_i(__float_as_int(wave_fmax(bestd))));
        unsigned long long bal = __ballot(bestd == wm);
        int L = (int)(__ffsll((long long)bal) - 1);
        unsigned widx = (unsigned)__builtin_amdgcn_readlane((int)bestp, L);

        if (lane == 0) {
            int wa = (int)(((widx & 31u) << 8) + (widx >> 5));
            unsigned* pp = part[it & 1][wid];
            pp[0] = 0xFFFFFFFFu - widx;
            pp[1] = __float_as_uint(wm);
            pp[2] = __float_as_uint(lx[wa]);
            pp[3] = __float_as_uint(ly[wa]);
            pp[4] = __float_as_uint(lz[wa]);
        }
        __syncthreads();

        // block reduce over 4 partials: lanes 0..3 hold parts 0..3; max valid in lane 3
        const unsigned* pp = part[it & 1][lane & 3];
        unsigned kl = pp[0], kh = pp[1];
        float xx = __uint_as_float(pp[2]);
        float yy = __uint_as_float(pp[3]);
        float zz = __uint_as_float(pp[4]);
        unsigned long long v = ((unsigned long long)kh << 32) | kl;
        U64_DPP_STEP(0x111, 0xF, >);
        U64_DPP_STEP(0x112, 0xF, >);
        unsigned wkl = (unsigned)__builtin_amdgcn_readlane((int)(unsigned)v, 3);
        cur = 0xFFFFFFFFu - wkl;
        int W = (int)(cur >> 11);   // 2048 pts per wave -> winning wave id
        cx = __int_as_float(__builtin_amdgcn_readlane(__float_as_int(xx), W));
        cy = __int_as_float(__builtin_amdgcn_readlane(__float_as_int(yy), W));
        cz = __int_as_float(__builtin_amdgcn_readlane(__float_as_int(zz), W));
    }
}

// ---------------- Kernel 2: 32-NN per (batch, group) ----------------------------------
// No big LDS: deep pops (rare) use a cndmask ladder over the sorted register array.
// LDS ~2.2 KB; (512,6) targets <=85 VGPR -> 3 resident blocks/CU.
extern "C" __global__ __launch_bounds__(K2_THREADS, 6) void knn_kernel(
    const float* __restrict__ xyz, const int* __restrict__ fps_idx,
    float* __restrict__ out)
{
    const int bg  = blockIdx.x;
    const int b   = bg >> 9;
    const int g   = bg & (NGROUP - 1);
    const int tid = threadIdx.x;
    const float* base = xyz + (size_t)b * N_PTS * 6;

    const int q  = fps_idx[b * NGROUP + g];
    const int qq = __builtin_amdgcn_readfirstlane(q);
    const float cx = base[qq * 6 + 0];
    const float cy = base[qq * 6 + 1];
    const float cz = base[qq * 6 + 2];
    // ||c||^2: separate square, left-assoc add, NO FMA
    const float cn = __fadd_rn(__fadd_rn(__fmul_rn(cx, cx), __fmul_rn(cy, cy)),
                               __fmul_rn(cz, cz));

    const float4* b4 = (const float4*)base;
    const int tb = tid * 24;

    unsigned long long keys[K2_PPT];

#pragma unroll
    for (int c = 0; c < 4; ++c) {
        float4 f0 = b4[tb + c * 6 + 0];
        float4 f1 = b4[tb + c * 6 + 1];
        float4 f2 = b4[tb + c * 6 + 2];
        float4 f3 = b4[tb + c * 6 + 3];
        float4 f4 = b4[tb + c * 6 + 4];
        float4 f5 = b4[tb + c * 6 + 5];
        float X[4] = {f0.x, f1.z, f3.x, f4.z};
        float Y[4] = {f0.y, f1.w, f3.y, f4.w};
        float Z[4] = {f0.z, f2.x, f3.z, f5.x};
#pragma unroll
        for (int j = 0; j < 4; ++j) {
            float x = X[j], y = Y[j], z = Z[j];
            float xn  = __fadd_rn(__fadd_rn(__fmul_rn(x, x), __fmul_rn(y, y)), __fmul_rn(z, z));
            float dot = __fmul_rn(cx, x);
            dot = __fmaf_rn(cy, y, dot);
            dot = __fmaf_rn(cz, z, dot);
            float d2  = __fadd_rn(__fsub_rn(cn, __fmul_rn(2.0f, dot)), xn);
            int p = tid * K2_PPT + c * 4 + j;
            keys[c * 4 + j] =
                ((unsigned long long)fxform(__float_as_uint(d2)) << 32) | (unsigned)p;
        }
    }

    bitonic_sort<K2_PPT>(keys);

    __shared__ unsigned long long wtop[K2_WAVES][GSIZE];   // 2 KB
    __shared__ unsigned nlist[GSIZE];

    const int wid  = tid >> 6;
    const int lane = tid & 63;

    // per-wave top-32 extraction (ascending into wtop[wid])
    {
        unsigned long long cand = keys[0];
        unsigned w = 0;
        for (int r = 0; r < GSIZE; ++r) {
            unsigned ch = (unsigned)(cand >> 32);
            unsigned whd = (unsigned)rdlane63_i((int)wave_umin32(ch));
            unsigned long long bal = __ballot(ch == whd);
            unsigned wl;
            if (__popcll(bal) == 1) {
                int L = (int)(__ffsll((long long)bal) - 1);
                wl = (unsigned)__builtin_amdgcn_readlane((int)(unsigned)cand, L);
            } else {
                unsigned cl = (ch == whd) ? (unsigned)cand : 0xFFFFFFFFu;
                wl = (unsigned)rdlane63_i((int)wave_umin32(cl));
            }
            unsigned long long wkey = ((unsigned long long)whd << 32) | wl;
            if (lane == 0) wtop[wid][r] = wkey;
            if (cand == wkey) {   // exactly one lane (keys unique)
                ++w;
                unsigned long long nc;
                if (w < 4) {
                    nc = (w == 1) ? keys[1] : (w == 2) ? keys[2] : keys[3];
                } else if (w < K2_PPT) {
                    // rare: cndmask ladder over sorted register array (1 lane active)
                    nc = keys[4];
#pragma unroll
                    for (int j = 5; j < K2_PPT; ++j) nc = (w == (unsigned)j) ? keys[j] : nc;
                } else {
                    nc = ~0ull;
                }
                cand = nc;
            }
        }
    }
    __syncthreads();

    // parallel rank-merge: 256 threads, one candidate each; rank = sum of lower_bounds
    if (tid < K2_WAVES * GSIZE) {
        const int w8 = tid >> 5, i = tid & 31;
        unsigned long long e = wtop[w8][i];
        int rank = 0;
#pragma unroll
        for (int l = 0; l < K2_WAVES; ++l) {
            const unsigned long long* arr = wtop[l];
            int lo = 0;
            if (arr[15]     < e) lo = 16;
            if (arr[lo + 7] < e) lo += 8;
            if (arr[lo + 3] < e) lo += 4;
            if (arr[lo + 1] < e) lo += 2;
            if (arr[lo]     < e) lo += 1;
            rank += lo;
        }
        if (rank < GSIZE) nlist[rank] = (unsigned)e;
    }
    __syncthreads();

    // ---- outputs ----
    const int OFF1 = N_B * NGROUP * GSIZE * 3;   // neigh_attr
    const int OFF2 = 2 * OFF1;                   // center
    const int OFF3 = OFF2 + N_B * NGROUP * 3;    // center_attribute

    if (tid < GSIZE) {
        unsigned p = nlist[tid];
        float x  = base[p * 6 + 0];
        float y  = base[p * 6 + 1];
        float z  = base[p * 6 + 2];
        float a0 = base[p * 6 + 3];
        float a1 = base[p * 6 + 4];
        float a2 = base[p * 6 + 5];
        size_t o = ((size_t)(b * NGROUP + g) * GSIZE + tid) * 3;
        out[o + 0] = __fsub_rn(x, cx);
        out[o + 1] = __fsub_rn(y, cy);
        out[o + 2] = __fsub_rn(z, cz);
        out[OFF1 + o + 0] = a0;
        out[OFF1 + o + 1] = a1;
        out[OFF1 + o + 2] = a2;
    } else if (tid == GSIZE) {
        size_t o = (size_t)(b * NGROUP + g) * 3;
        out[OFF2 + o + 0] = cx;
        out[OFF2 + o + 1] = cy;
        out[OFF2 + o + 2] = cz;
        out[OFF3 + o + 0] = base[qq * 6 + 3];
        out[OFF3 + o + 1] = base[qq * 6 + 4];
        out[OFF3 + o + 2] = base[qq * 6 + 5];
    }
}

extern "C" void kernel_launch(void* const* d_in, const int* in_sizes, int n_in,
                              void* d_out, int out_size, void* d_ws, size_t ws_size,
                              hipStream_t stream) {
    const float* xyz = (const float*)d_in[0];
    float* out = (float*)d_out;
    int* fps_idx = (int*)d_ws;   // 8*512 ints = 16 KB

    fps_kernel<<<N_B, K1_THREADS, 0, stream>>>(xyz, fps_idx);
    knn_kernel<<<N_B * NGROUP, K2_THREADS, 0, stream>>>(xyz, fps_idx, out);
}